// Round 3
// baseline (3565.451 us; speedup 1.0000x reference)
//
#include <hip/hip_runtime.h>

#define NSTEP 16
#define BATCH 65536
#define DD 64
#define HH 256
#define MT 64           // rows per block
#define H0S 264         // padded LDS stride (elems) for 256-wide activations
#define ABSTR 72        // padded LDS stride (elems) for 64-wide layer0 input

typedef _Float16 half8 __attribute__((ext_vector_type(8)));
typedef float floatx4 __attribute__((ext_vector_type(4)));

// ---------------- prep: transpose + fp16-cast weights into d_ws ----------------
// ws layout (elems): Wt0 [256][64] @ 0 ; Wt1 [256][256] @ 16384 ; Wt2 [64][256] @ 81920
__global__ __launch_bounds__(256) void prep_weights(
    const float* __restrict__ W0, const float* __restrict__ W1,
    const float* __restrict__ W2, _Float16* __restrict__ ws)
{
    int i = blockIdx.x * 256 + threadIdx.x;      // 0..65535 (256 blocks)
    _Float16* Wt0 = ws;
    _Float16* Wt1 = ws + 16384;
    _Float16* Wt2 = ws + 16384 + 65536;
    { int n = i >> 8, k = i & 255; Wt1[i] = (_Float16)W1[k * HH + n]; }
    if (i < 16384) {
        { int n = i >> 6, k = i & 63;  Wt0[i] = (_Float16)W0[k * HH + n]; }
        { int n = i >> 8, k = i & 255; Wt2[i] = (_Float16)W2[k * DD + n]; }
    }
}

// ---------------- one MLP forward ----------------
// MODE 0: base pass (k1) + generate ReLU masks into m0/m1
// MODE 1: masked-linear JVP pass (uses m0/m1, no biases)
// MODE 2: plain pass (k2/k3/k4)
// A-frag: A[m=lane&15][k=quad*8+j]; B-frag: B[k=quad*8+j][n=lane&15];
// C/D:    col=lane&15, row=quad*4+reg  (guide-verified layouts, 16x16x32)
template<int MODE>
__device__ __forceinline__ void mlp_pass(
    const _Float16* __restrict__ Wt0, const _Float16* __restrict__ Wt1,
    const _Float16* __restrict__ Wt2,
    const float* b1v, float b2v,
    _Float16* h0, _Float16* h1, const _Float16* ab, const float* c0buf,
    int wave, int quad, int l16, float* outv,
    unsigned long long& m0, unsigned long long& m1)
{
    const floatx4 zero4 = {0.f, 0.f, 0.f, 0.f};

    // ---------- layer 0: [64x64] @ [64x256] ----------
    floatx4 acc[4][4];
#pragma unroll
    for (int rt = 0; rt < 4; rt++)
#pragma unroll
        for (int ct = 0; ct < 4; ct++) acc[rt][ct] = zero4;
#pragma unroll
    for (int kc = 0; kc < 2; kc++) {
        half8 af[4], bf[4];
#pragma unroll
        for (int rt = 0; rt < 4; rt++)
            af[rt] = *(const half8*)(ab + (rt * 16 + l16) * ABSTR + kc * 32 + quad * 8);
#pragma unroll
        for (int ct = 0; ct < 4; ct++)
            bf[ct] = *(const half8*)(Wt0 + (wave * 64 + ct * 16 + l16) * DD + kc * 32 + quad * 8);
#pragma unroll
        for (int rt = 0; rt < 4; rt++)
#pragma unroll
            for (int ct = 0; ct < 4; ct++)
                acc[rt][ct] = __builtin_amdgcn_mfma_f32_16x16x32_f16(af[rt], bf[ct], acc[rt][ct], 0, 0, 0);
    }
    {
        unsigned long long mnew = 0;
#pragma unroll
        for (int ct = 0; ct < 4; ct++) {
            int col = wave * 64 + ct * 16 + l16;
            float cb = (MODE == 1) ? 0.f : c0buf[col];
#pragma unroll
            for (int rt = 0; rt < 4; rt++)
#pragma unroll
                for (int rr = 0; rr < 4; rr++) {
                    int row = rt * 16 + quad * 4 + rr;
                    int idx = (ct << 4) | (rt << 2) | rr;
                    float v = acc[rt][ct][rr];
                    bool pos;
                    if (MODE == 1) {
                        pos = (m0 >> idx) & 1ull;
                    } else {
                        v += cb;
                        pos = v > 0.f;
                        if (MODE == 0) mnew |= (unsigned long long)pos << idx;
                    }
                    h0[row * H0S + col] = pos ? (_Float16)v : (_Float16)0.f;
                }
        }
        if (MODE == 0) m0 = mnew;
    }
    __syncthreads();

    // ---------- layer 1: [64x256] @ [256x256] ----------
#pragma unroll
    for (int rt = 0; rt < 4; rt++)
#pragma unroll
        for (int ct = 0; ct < 4; ct++) acc[rt][ct] = zero4;
#pragma unroll
    for (int kc = 0; kc < 8; kc++) {
        half8 af[4], bf[4];
#pragma unroll
        for (int rt = 0; rt < 4; rt++)
            af[rt] = *(const half8*)(h0 + (rt * 16 + l16) * H0S + kc * 32 + quad * 8);
#pragma unroll
        for (int ct = 0; ct < 4; ct++)
            bf[ct] = *(const half8*)(Wt1 + (wave * 64 + ct * 16 + l16) * HH + kc * 32 + quad * 8);
#pragma unroll
        for (int rt = 0; rt < 4; rt++)
#pragma unroll
            for (int ct = 0; ct < 4; ct++)
                acc[rt][ct] = __builtin_amdgcn_mfma_f32_16x16x32_f16(af[rt], bf[ct], acc[rt][ct], 0, 0, 0);
    }
    {
        unsigned long long mnew = 0;
#pragma unroll
        for (int ct = 0; ct < 4; ct++) {
            float cb = (MODE == 1) ? 0.f : b1v[ct];
            int col = wave * 64 + ct * 16 + l16;
#pragma unroll
            for (int rt = 0; rt < 4; rt++)
#pragma unroll
                for (int rr = 0; rr < 4; rr++) {
                    int row = rt * 16 + quad * 4 + rr;
                    int idx = (ct << 4) | (rt << 2) | rr;
                    float v = acc[rt][ct][rr];
                    bool pos;
                    if (MODE == 1) {
                        pos = (m1 >> idx) & 1ull;
                    } else {
                        v += cb;
                        pos = v > 0.f;
                        if (MODE == 0) mnew |= (unsigned long long)pos << idx;
                    }
                    h1[row * H0S + col] = pos ? (_Float16)v : (_Float16)0.f;
                }
        }
        if (MODE == 0) m1 = mnew;
    }
    __syncthreads();

    // ---------- layer 2: [64x256] @ [256x64] ----------
    floatx4 a2[4];
#pragma unroll
    for (int rt = 0; rt < 4; rt++) a2[rt] = zero4;
#pragma unroll
    for (int kc = 0; kc < 8; kc++) {
        half8 bf2 = *(const half8*)(Wt2 + (wave * 16 + l16) * HH + kc * 32 + quad * 8);
#pragma unroll
        for (int rt = 0; rt < 4; rt++) {
            half8 af = *(const half8*)(h1 + (rt * 16 + l16) * H0S + kc * 32 + quad * 8);
            a2[rt] = __builtin_amdgcn_mfma_f32_16x16x32_f16(af, bf2, a2[rt], 0, 0, 0);
        }
    }
    float bb2 = (MODE == 1) ? 0.f : b2v;
#pragma unroll
    for (int rt = 0; rt < 4; rt++)
#pragma unroll
        for (int rr = 0; rr < 4; rr++) outv[rt * 4 + rr] = a2[rt][rr] + bb2;
    // no trailing sync; next pass's ab-write + pre-layer0 sync covers reuse
}

// ---------------- main: 64 rows per block, full 16-step integration ----------------
// LDS (78 KB) caps at 2 blocks/CU, so pin 2 waves/EU -> full 256-VGPR budget,
// no scratch spills (round-2 showed 631 MB of spill WRITE_SIZE at VGPR=128).
__global__ __attribute__((amdgpu_flat_work_group_size(256, 256), amdgpu_waves_per_eu(2, 2)))
void ffjord_kernel(
    const float* __restrict__ xg, const float* __restrict__ epsg,
    const float* __restrict__ W0g, const float* __restrict__ b0g,
    const float* __restrict__ b1g, const float* __restrict__ b2g,
    const _Float16* __restrict__ ws, float* __restrict__ out)
{
    __shared__ __attribute__((aligned(16))) _Float16 h0[MT * H0S];
    __shared__ __attribute__((aligned(16))) _Float16 h1[MT * H0S];
    __shared__ __attribute__((aligned(16))) _Float16 ab[MT * ABSTR];
    __shared__ float c0buf[HH];
    __shared__ float ldacc[MT];

    const _Float16* Wt0 = ws;
    const _Float16* Wt1 = ws + 16384;
    const _Float16* Wt2 = ws + 16384 + 65536;

    const int tid  = threadIdx.x;
    const int wave = tid >> 6;
    const int lane = tid & 63;
    const int quad = lane >> 4;
    const int l16  = lane & 15;
    const int row0 = blockIdx.x * MT;
    const int colD = wave * 16 + l16;          // this lane's state column (layer-2 C layout)
    const float dt = 1.f / NSTEP;

    // preload uniform-ish data into registers (removes per-pass global loads)
    const float wtime = W0g[64 * HH + tid];    // time-feature row of W0 for this h-col
    const float b0v   = b0g[tid];
    float b1v[4];
#pragma unroll
    for (int ct = 0; ct < 4; ct++) b1v[ct] = b1g[wave * 64 + ct * 16 + l16];
    const float b2v = b2g[wave * 16 + l16];

    if (tid < MT) ldacc[tid] = 0.f;

    float x[16];
#pragma unroll
    for (int i = 0; i < 16; i++) {
        int r = (i >> 2) * 16 + quad * 4 + (i & 3);
        x[i] = xg[(size_t)(row0 + r) * DD + colD];
    }
    float ldreg[16];
#pragma unroll
    for (int i = 0; i < 16; i++) ldreg[i] = 0.f;

    unsigned long long m0 = 0, m1 = 0;

#pragma unroll 1
    for (int s = 0; s < NSTEP; s++) {
        float t = s * dt;
        float xacc[16], kprev[16], outv[16];
#pragma unroll
        for (int i = 0; i < 16; i++) { xacc[i] = x[i]; kprev[i] = 0.f; }

        // pass order: 0=base(k1)+masks, 1=jvp(masked), 2=k2, 3=k3, 4=k4
#pragma unroll 1
        for (int p = 0; p < 5; p++) {
            if (p == 1) {
                float e[16];
#pragma unroll
                for (int i = 0; i < 16; i++) {
                    int r = (i >> 2) * 16 + quad * 4 + (i & 3);
                    e[i] = epsg[(size_t)(s * BATCH + row0 + r) * DD + colD];
                }
#pragma unroll
                for (int i = 0; i < 16; i++) {
                    int r = (i >> 2) * 16 + quad * 4 + (i & 3);
                    ab[r * ABSTR + colD] = (_Float16)(0.5f * e[i]);
                }
                __syncthreads();
                mlp_pass<1>(Wt0, Wt1, Wt2, b1v, b2v, h0, h1, ab, c0buf,
                            wave, quad, l16, outv, m0, m1);
                // per-lane partial of trace = sum_col e * (0.5e + dMLP); reduce at end
#pragma unroll
                for (int i = 0; i < 16; i++)
                    ldreg[i] -= dt * (e[i] * (0.5f * e[i] + outv[i]));
            } else {
                float c  = (p == 4) ? 1.f : 0.5f;                 // y = x + c*dt*kprev
                float w  = (p == 0 || p == 4) ? dt / 6.f : dt / 3.f;
                float tp = t + ((p == 4) ? dt : (p >= 2 ? 0.5f * dt : 0.f));
                float yv[16];
#pragma unroll
                for (int i = 0; i < 16; i++) yv[i] = x[i] + c * dt * kprev[i];
#pragma unroll
                for (int i = 0; i < 16; i++) {
                    int r = (i >> 2) * 16 + quad * 4 + (i & 3);
                    ab[r * ABSTR + colD] = (_Float16)yv[i];
                }
                // c0 = t*W0[time-row] + b0 folds the time feature (layer0 runs K=64)
                c0buf[tid] = tp * wtime + b0v;
                __syncthreads();
                if (p == 0)
                    mlp_pass<0>(Wt0, Wt1, Wt2, b1v, b2v, h0, h1, ab, c0buf,
                                wave, quad, l16, outv, m0, m1);
                else
                    mlp_pass<2>(Wt0, Wt1, Wt2, b1v, b2v, h0, h1, ab, c0buf,
                                wave, quad, l16, outv, m0, m1);
#pragma unroll
                for (int i = 0; i < 16; i++) {
                    kprev[i] = yv[i] + outv[i];                   // k = y + MLP(y)  (residual)
                    xacc[i] += w * kprev[i];
                }
            }
        }
#pragma unroll
        for (int i = 0; i < 16; i++) x[i] = xacc[i];
    }

    // outputs: x_out [B,D] then log_det [B]
#pragma unroll
    for (int i = 0; i < 16; i++) {
        int r = (i >> 2) * 16 + quad * 4 + (i & 3);
        out[(size_t)(row0 + r) * DD + colD] = x[i];
    }
    // log_det: reduce per-lane partials over the 16 l16 lanes, then across waves
#pragma unroll
    for (int i = 0; i < 16; i++) {
        float pr = ldreg[i];
        pr += __shfl_xor(pr, 1);
        pr += __shfl_xor(pr, 2);
        pr += __shfl_xor(pr, 4);
        pr += __shfl_xor(pr, 8);
        if (l16 == 0) {
            int r = (i >> 2) * 16 + quad * 4 + (i & 3);
            atomicAdd(&ldacc[r], pr);
        }
    }
    __syncthreads();
    if (tid < MT) out[(size_t)BATCH * DD + row0 + tid] = ldacc[tid];
}

extern "C" void kernel_launch(void* const* d_in, const int* in_sizes, int n_in,
                              void* d_out, int out_size, void* d_ws, size_t ws_size,
                              hipStream_t stream) {
    const float* xg   = (const float*)d_in[0];
    const float* epsg = (const float*)d_in[1];
    const float* W0g  = (const float*)d_in[2];
    const float* b0g  = (const float*)d_in[3];
    const float* W1g  = (const float*)d_in[4];
    const float* b1g  = (const float*)d_in[5];
    const float* W2g  = (const float*)d_in[6];
    const float* b2g  = (const float*)d_in[7];
    float* outp = (float*)d_out;
    _Float16* ws = (_Float16*)d_ws;

    prep_weights<<<65536 / 256, 256, 0, stream>>>(W0g, W1g, W2g, ws);
    ffjord_kernel<<<BATCH / MT, 256, 0, stream>>>(xg, epsg, W0g, b0g, b1g, b2g, ws, outp);
}

// Round 4
// 2967.748 us; speedup vs baseline: 1.2014x; 1.2014x over previous
//
#include <hip/hip_runtime.h>

#define NSTEP 16
#define BATCH 65536
#define DD 64
#define HH 256
#define MT 64           // rows per block
#define H0S 264         // padded LDS stride (fp16) for 256-wide activations
#define ABSTR 72        // padded LDS stride (fp16) for 64-wide layer0 input
#define XS 68           // padded per-column stride for state arrays

typedef _Float16 half8 __attribute__((ext_vector_type(8)));
typedef _Float16 half4 __attribute__((ext_vector_type(4)));
typedef float floatx4 __attribute__((ext_vector_type(4)));

// ---------------- prep: transpose + fp16-cast weights into d_ws ----------------
// ws layout (elems): Wt0 [256][64] @ 0 ; Wt1 [256][256] @ 16384 ; Wt2 [64][256] @ 81920
__global__ __launch_bounds__(256) void prep_weights(
    const float* __restrict__ W0, const float* __restrict__ W1,
    const float* __restrict__ W2, _Float16* __restrict__ ws)
{
    int i = blockIdx.x * 256 + threadIdx.x;      // 0..65535 (256 blocks)
    _Float16* Wt0 = ws;
    _Float16* Wt1 = ws + 16384;
    _Float16* Wt2 = ws + 16384 + 65536;
    { int n = i >> 8, k = i & 255; Wt1[i] = (_Float16)W1[k * HH + n]; }
    if (i < 16384) {
        { int n = i >> 6, k = i & 63;  Wt0[i] = (_Float16)W0[k * HH + n]; }
        { int n = i >> 8, k = i & 255; Wt2[i] = (_Float16)W2[k * DD + n]; }
    }
}

// ---------------- one MLP forward ----------------
// MODE 0: base pass (k1) + generate ReLU masks into m0/m1
// MODE 1: masked-linear JVP pass (uses m0/m1, no biases)
// MODE 2: plain pass (k2/k3/k4)
// Single h buffer: barrier between L1-read loop and L1-epilogue write.
// A-frag: A[m=lane&15][k=quad*8+j]; B-frag: B[k=quad*8+j][n=lane&15];
// C/D:    col=lane&15, row=quad*4+reg
template<int MODE>
__device__ __forceinline__ void mlp_pass(
    const _Float16* __restrict__ Wt0, const _Float16* __restrict__ Wt1,
    const _Float16* __restrict__ Wt2,
    const float* b1v, float b2v,
    _Float16* h, const _Float16* ab, const float* c0buf,
    int wave, int quad, int l16, float* outv,
    unsigned long long& m0, unsigned long long& m1)
{
    const floatx4 zero4 = {0.f, 0.f, 0.f, 0.f};

    // ---------- layer 0: [64x64] @ [64x256] ----------
    floatx4 acc[4][4];
#pragma unroll
    for (int rt = 0; rt < 4; rt++)
#pragma unroll
        for (int ct = 0; ct < 4; ct++) acc[rt][ct] = zero4;
#pragma unroll
    for (int kc = 0; kc < 2; kc++) {
        half8 af[4], bf[4];
#pragma unroll
        for (int rt = 0; rt < 4; rt++)
            af[rt] = *(const half8*)(ab + (rt * 16 + l16) * ABSTR + kc * 32 + quad * 8);
#pragma unroll
        for (int ct = 0; ct < 4; ct++)
            bf[ct] = *(const half8*)(Wt0 + (wave * 64 + ct * 16 + l16) * DD + kc * 32 + quad * 8);
#pragma unroll
        for (int rt = 0; rt < 4; rt++)
#pragma unroll
            for (int ct = 0; ct < 4; ct++)
                acc[rt][ct] = __builtin_amdgcn_mfma_f32_16x16x32_f16(af[rt], bf[ct], acc[rt][ct], 0, 0, 0);
    }
    {
        unsigned long long mnew = 0;
#pragma unroll
        for (int ct = 0; ct < 4; ct++) {
            int col = wave * 64 + ct * 16 + l16;
            float cb = (MODE == 1) ? 0.f : c0buf[col];
#pragma unroll
            for (int rt = 0; rt < 4; rt++)
#pragma unroll
                for (int rr = 0; rr < 4; rr++) {
                    int row = rt * 16 + quad * 4 + rr;
                    int idx = (ct << 4) | (rt << 2) | rr;
                    float v = acc[rt][ct][rr];
                    bool pos;
                    if (MODE == 1) {
                        pos = (m0 >> idx) & 1ull;
                    } else {
                        v += cb;
                        pos = v > 0.f;
                        if (MODE == 0) mnew |= (unsigned long long)pos << idx;
                    }
                    h[row * H0S + col] = pos ? (_Float16)v : (_Float16)0.f;
                }
        }
        if (MODE == 0) m0 = mnew;
    }
    __syncthreads();   // B: h(z0) visible to all

    // ---------- layer 1: [64x256] @ [256x256] ----------
#pragma unroll
    for (int rt = 0; rt < 4; rt++)
#pragma unroll
        for (int ct = 0; ct < 4; ct++) acc[rt][ct] = zero4;
#pragma unroll
    for (int kc = 0; kc < 8; kc++) {
        half8 af[4], bf[4];
#pragma unroll
        for (int rt = 0; rt < 4; rt++)
            af[rt] = *(const half8*)(h + (rt * 16 + l16) * H0S + kc * 32 + quad * 8);
#pragma unroll
        for (int ct = 0; ct < 4; ct++)
            bf[ct] = *(const half8*)(Wt1 + (wave * 64 + ct * 16 + l16) * HH + kc * 32 + quad * 8);
#pragma unroll
        for (int rt = 0; rt < 4; rt++)
#pragma unroll
            for (int ct = 0; ct < 4; ct++)
                acc[rt][ct] = __builtin_amdgcn_mfma_f32_16x16x32_f16(af[rt], bf[ct], acc[rt][ct], 0, 0, 0);
    }
    __syncthreads();   // C: all reads of h(z0) done before in-place overwrite
    {
        unsigned long long mnew = 0;
#pragma unroll
        for (int ct = 0; ct < 4; ct++) {
            float cb = (MODE == 1) ? 0.f : b1v[ct];
            int col = wave * 64 + ct * 16 + l16;
#pragma unroll
            for (int rt = 0; rt < 4; rt++)
#pragma unroll
                for (int rr = 0; rr < 4; rr++) {
                    int row = rt * 16 + quad * 4 + rr;
                    int idx = (ct << 4) | (rt << 2) | rr;
                    float v = acc[rt][ct][rr];
                    bool pos;
                    if (MODE == 1) {
                        pos = (m1 >> idx) & 1ull;
                    } else {
                        v += cb;
                        pos = v > 0.f;
                        if (MODE == 0) mnew |= (unsigned long long)pos << idx;
                    }
                    h[row * H0S + col] = pos ? (_Float16)v : (_Float16)0.f;
                }
        }
        if (MODE == 0) m1 = mnew;
    }
    __syncthreads();   // D: h(z1) visible to all

    // ---------- layer 2: [64x256] @ [256x64] ----------
    floatx4 a2[4];
#pragma unroll
    for (int rt = 0; rt < 4; rt++) a2[rt] = zero4;
#pragma unroll
    for (int kc = 0; kc < 8; kc++) {
        half8 bf2 = *(const half8*)(Wt2 + (wave * 16 + l16) * HH + kc * 32 + quad * 8);
#pragma unroll
        for (int rt = 0; rt < 4; rt++) {
            half8 af = *(const half8*)(h + (rt * 16 + l16) * H0S + kc * 32 + quad * 8);
            a2[rt] = __builtin_amdgcn_mfma_f32_16x16x32_f16(af, bf2, a2[rt], 0, 0, 0);
        }
    }
    float bb2 = (MODE == 1) ? 0.f : b2v;
#pragma unroll
    for (int rt = 0; rt < 4; rt++)
#pragma unroll
        for (int rr = 0; rr < 4; rr++) outv[rt * 4 + rr] = a2[rt][rr] + bb2;
    // next pass's barrier A covers ab/c0buf/h reuse
}

// ---------------- main: 64 rows per block, state LDS-resident ----------------
// LDS 79.4 KB -> 2 blocks/CU. Per-lane persistent registers ~tiny: all RK4
// state (x fp32, kprev fp16, S fp16) lives in thread-exclusive LDS slots.
__global__ __launch_bounds__(256, 2) void ffjord_kernel(
    const float* __restrict__ xg, const float* __restrict__ epsg,
    const float* __restrict__ W0g, const float* __restrict__ b0g,
    const float* __restrict__ b1g, const float* __restrict__ b2g,
    const _Float16* __restrict__ ws, float* __restrict__ out)
{
    __shared__ __attribute__((aligned(16))) _Float16 h[MT * H0S];     // 33792 B
    __shared__ __attribute__((aligned(16))) _Float16 ab[MT * ABSTR];  //  9216 B
    __shared__ __attribute__((aligned(16))) float    xs[DD * XS];     // 17408 B [col][row]
    __shared__ __attribute__((aligned(16))) _Float16 kps[DD * XS];    //  8704 B
    __shared__ __attribute__((aligned(16))) _Float16 Ss[DD * XS];     //  8704 B
    __shared__ float c0buf[HH];                                       //  1024 B
    __shared__ float ldacc[4 * MT];                                   //  1024 B

    const _Float16* Wt0 = ws;
    const _Float16* Wt1 = ws + 16384;
    const _Float16* Wt2 = ws + 16384 + 65536;

    const int tid  = threadIdx.x;
    const int wave = tid >> 6;
    const int lane = tid & 63;
    const int quad = lane >> 4;
    const int l16  = lane & 15;
    const int row0 = blockIdx.x * MT;
    const int colD = wave * 16 + l16;          // this lane's state column
    const float dt = 1.f / NSTEP;

    const float wtime = W0g[64 * HH + tid];    // time-feature row of W0
    const float b0v   = b0g[tid];
    float b1v[4];
#pragma unroll
    for (int ct = 0; ct < 4; ct++) b1v[ct] = b1g[wave * 64 + ct * 16 + l16];
    const float b2v = b2g[wave * 16 + l16];

    ldacc[tid] = 0.f;

    // load x into own LDS slots (thread-exclusive; no barrier needed for self-use)
#pragma unroll
    for (int i = 0; i < 16; i++) {
        int r = (i >> 2) * 16 + quad * 4 + (i & 3);
        xs[colD * XS + r] = xg[(size_t)(row0 + r) * DD + colD];
    }

    unsigned long long m0 = 0, m1 = 0;
    const int sbase = colD * XS + quad * 4;    // base of this lane's state slots

#pragma unroll 1
    for (int s = 0; s < NSTEP; s++) {
        float t = s * dt;
        float outv[16];

#pragma unroll 1
        for (int p = 0; p < 5; p++) {
            if (p == 1) {
                // ---- JVP pass: ab = fp16(0.5*e) ----
#pragma unroll
                for (int i = 0; i < 16; i++) {
                    int r = (i >> 2) * 16 + quad * 4 + (i & 3);
                    float e = epsg[((size_t)s * BATCH + row0 + r) * DD + colD];
                    ab[r * ABSTR + colD] = (_Float16)(0.5f * e);
                }
                __syncthreads();   // A
                mlp_pass<1>(Wt0, Wt1, Wt2, b1v, b2v, h, ab, c0buf,
                            wave, quad, l16, outv, m0, m1);
                // trace partial: e ~= 2*ab; pr = 2*ab*(ab + outv); per-wave slot, no atomics
#pragma unroll
                for (int i = 0; i < 16; i++) {
                    int r = (i >> 2) * 16 + quad * 4 + (i & 3);
                    float abv = (float)ab[r * ABSTR + colD];
                    float pr = 2.f * abv * (abv + outv[i]);
                    pr += __shfl_xor(pr, 1);
                    pr += __shfl_xor(pr, 2);
                    pr += __shfl_xor(pr, 4);
                    pr += __shfl_xor(pr, 8);
                    if (l16 == 0) ldacc[wave * 64 + r] -= dt * pr;
                }
            } else {
                float cc = (p == 4) ? dt : (p == 0 ? 0.f : 0.5f * dt);
                float tp = t + ((p == 4) ? dt : (p >= 2 ? 0.5f * dt : 0.f));
                // ---- write ab = fp16(yv), yv = x + cc*kprev ----
#pragma unroll
                for (int rt = 0; rt < 4; rt++) {
                    floatx4 xv = *(const floatx4*)(xs + sbase + rt * 16);
                    half4 kv;
                    if (p != 0) kv = *(const half4*)(kps + sbase + rt * 16);
#pragma unroll
                    for (int rr = 0; rr < 4; rr++) {
                        float yv = xv[rr] + (p == 0 ? 0.f : cc * (float)kv[rr]);
                        int r = rt * 16 + quad * 4 + rr;
                        ab[r * ABSTR + colD] = (_Float16)yv;
                    }
                }
                c0buf[tid] = tp * wtime + b0v;     // fold time feature + b0
                __syncthreads();   // A
                if (p == 0)
                    mlp_pass<0>(Wt0, Wt1, Wt2, b1v, b2v, h, ab, c0buf,
                                wave, quad, l16, outv, m0, m1);
                else
                    mlp_pass<2>(Wt0, Wt1, Wt2, b1v, b2v, h, ab, c0buf,
                                wave, quad, l16, outv, m0, m1);
                // ---- state update: k = yv + outv ; S += w*k ; kprev = k ----
#pragma unroll
                for (int rt = 0; rt < 4; rt++) {
                    floatx4 xv = *(const floatx4*)(xs + sbase + rt * 16);
                    if (p == 0) {
                        half4 kn, sn;
#pragma unroll
                        for (int rr = 0; rr < 4; rr++) {
                            float k = xv[rr] + outv[rt * 4 + rr];
                            kn[rr] = (_Float16)k;
                            sn[rr] = (_Float16)k;                  // S = k1
                        }
                        *(half4*)(kps + sbase + rt * 16) = kn;
                        *(half4*)(Ss + sbase + rt * 16) = sn;
                    } else if (p == 4) {
                        half4 kv = *(const half4*)(kps + sbase + rt * 16);
                        half4 sv = *(const half4*)(Ss + sbase + rt * 16);
                        floatx4 xn;
#pragma unroll
                        for (int rr = 0; rr < 4; rr++) {
                            float yv = xv[rr] + cc * (float)kv[rr];
                            float k  = yv + outv[rt * 4 + rr];
                            float Sf = (float)sv[rr] + k;          // + k4
                            xn[rr] = xv[rr] + (dt / 6.f) * Sf;
                        }
                        *(floatx4*)(xs + sbase + rt * 16) = xn;
                    } else {
                        half4 kv = *(const half4*)(kps + sbase + rt * 16);
                        half4 sv = *(const half4*)(Ss + sbase + rt * 16);
                        half4 kn, sn;
#pragma unroll
                        for (int rr = 0; rr < 4; rr++) {
                            float yv = xv[rr] + cc * (float)kv[rr];
                            float k  = yv + outv[rt * 4 + rr];
                            kn[rr] = (_Float16)k;
                            sn[rr] = (_Float16)((float)sv[rr] + 2.f * k);   // + 2*k2 / 2*k3
                        }
                        *(half4*)(kps + sbase + rt * 16) = kn;
                        *(half4*)(Ss + sbase + rt * 16) = sn;
                    }
                }
            }
        }
    }

    // outputs: x_out [B,D] then log_det [B]
#pragma unroll
    for (int i = 0; i < 16; i++) {
        int r = (i >> 2) * 16 + quad * 4 + (i & 3);
        out[(size_t)(row0 + r) * DD + colD] = xs[colD * XS + r];
    }
    __syncthreads();
    if (tid < MT) {
        float v = ldacc[tid] + ldacc[64 + tid] + ldacc[128 + tid] + ldacc[192 + tid];
        out[(size_t)BATCH * DD + row0 + tid] = v;
    }
}

extern "C" void kernel_launch(void* const* d_in, const int* in_sizes, int n_in,
                              void* d_out, int out_size, void* d_ws, size_t ws_size,
                              hipStream_t stream) {
    const float* xg   = (const float*)d_in[0];
    const float* epsg = (const float*)d_in[1];
    const float* W0g  = (const float*)d_in[2];
    const float* b0g  = (const float*)d_in[3];
    const float* W1g  = (const float*)d_in[4];
    const float* b1g  = (const float*)d_in[5];
    const float* W2g  = (const float*)d_in[6];
    const float* b2g  = (const float*)d_in[7];
    float* outp = (float*)d_out;
    _Float16* ws = (_Float16*)d_ws;

    prep_weights<<<65536 / 256, 256, 0, stream>>>(W0g, W1g, W2g, ws);
    ffjord_kernel<<<BATCH / MT, 256, 0, stream>>>(xg, epsg, W0g, b0g, b1g, b2g, ws, outp);
}